// Round 8
// baseline (1020.055 us; speedup 1.0000x reference)
//
#include <hip/hip_runtime.h>
#include <hip/hip_bf16.h>

// Problem: out = lecac_linear(relu(lecac_linear(x, W1, b1)), W2, b2)
//   x: [262144, 256] f32, W1: [512,256], b1: [512], W2: [256,512], b2: [256]
// R8: R4-R7 all spilled (FETCH 3x ideal) because register x-prefetch (xv) +
// code regs + frags exceeded the arch-VGPR budget. Fix: x is DMA'd to LDS as
// raw f32 via global_load_lds (pre-swizzled GLOBAL address, linear LDS dest,
// m173 pattern), converted to bf16 at fragment read. No xv registers, true
// async prefetch under counted vmcnt(8) (stores stay in flight). Biases live
// in LDS so their loads are lgkm-counted (can't force a vmcnt drain of the
// DMA). Weights stay packed 2-bit codes in 64 VGPRs, unpacked via v_perm LUT.

typedef __attribute__((ext_vector_type(8))) short bf16x8;
typedef __attribute__((ext_vector_type(4))) float f32x4;
typedef __attribute__((ext_vector_type(4))) unsigned short us4;

#define D_IN 256
#define D_HID 512
#define D_OUT 256
#define BM 64
#define TILES 8

__device__ __forceinline__ unsigned short f2bf(float f) {
  union { __hip_bfloat16 h; unsigned short u; } c;
  c.h = __float2bfloat16(f);
  return c.u;
}

__device__ __forceinline__ bf16x8 cvt8(float4 lo, float4 hi) {
  bf16x8 v;
  v[0] = (short)f2bf(lo.x); v[1] = (short)f2bf(lo.y);
  v[2] = (short)f2bf(lo.z); v[3] = (short)f2bf(lo.w);
  v[4] = (short)f2bf(hi.x); v[5] = (short)f2bf(hi.y);
  v[6] = (short)f2bf(hi.z); v[7] = (short)f2bf(hi.w);
  return v;
}

// DMA 16B per lane: global (per-lane addr) -> LDS (wave-uniform base + lane*16)
__device__ __forceinline__ void gload_lds16(const float* g, float* l) {
  __builtin_amdgcn_global_load_lds(
      (const __attribute__((address_space(1))) void*)(const void*)g,
      (__attribute__((address_space(3))) void*)(void*)l, 16, 0, 0);
}

// Unpack 8 codes (half of a 16-code u32, selected by kkl) -> bf16x8.
// Code c (2 bits): 0->0.0, 1->1.0, 2->-2.0, 3->-1.0. (verified R7)
__device__ __forceinline__ bf16x8 unpack8(unsigned w, int kkl) {
  unsigned te = (w >> (4 * kkl)) & 0x03030303u;        // els j = 0,2,4,6
  unsigned to = (w >> (4 * kkl + 2)) & 0x03030303u;    // els j = 1,3,5,7
  int4 o;
  unsigned s;
  s = __builtin_amdgcn_perm(to, te, 0x04040000u) + 0x00040004u;
  o.x = (int)__builtin_amdgcn_perm(0x80008000u, 0xBFC03F00u, s);
  s = __builtin_amdgcn_perm(to, te, 0x05050101u) + 0x00040004u;
  o.y = (int)__builtin_amdgcn_perm(0x80008000u, 0xBFC03F00u, s);
  s = __builtin_amdgcn_perm(to, te, 0x06060202u) + 0x00040004u;
  o.z = (int)__builtin_amdgcn_perm(0x80008000u, 0xBFC03F00u, s);
  s = __builtin_amdgcn_perm(to, te, 0x07070303u) + 0x00040004u;
  o.w = (int)__builtin_amdgcn_perm(0x80008000u, 0xBFC03F00u, s);
  return *(bf16x8*)&o;
}

// ---- prep 1: deterministic f64 partial abs-sums (8 chunks per tensor) ------
__global__ void partial_abs_kernel(const float* __restrict__ W1,
                                   const float* __restrict__ W2,
                                   double* __restrict__ part) {
  const int b = blockIdx.x;                 // 0..15
  const float* W = (b < 8) ? W1 : W2;
  const float* p = W + (b & 7) * 16384;     // 131072 / 8
  double s = 0.0;
  for (int i = threadIdx.x; i < 16384; i += 1024) s += (double)fabsf(p[i]);
  __shared__ double red[1024];
  red[threadIdx.x] = s;
  __syncthreads();
  for (int st = 512; st > 0; st >>= 1) {
    if (threadIdx.x < st) red[threadIdx.x] += red[threadIdx.x + st];
    __syncthreads();
  }
  if (threadIdx.x == 0) part[b] = red[0];
}

// ---- prep 2: pack 2-bit codes in the per-lane fragment order ---------------
// Word w' for owner thread t (0..511): W1: w' = mf*4+kp (mf<8,kp<4);
// W2: w' = mf*8+kp (mf<4,kp<8). Crumb (byte b, crumb c): j=2b+(c&1), kkl=c>>1.
// W1 frag: row = 128*(wv>>1)+16mf+l15, k = (2kp+kkl)*32+8g+j.
// W2 frag: row = 64*(wv>>1)+16mf+l15,  k = (2kp+kkl)*32+8g+j.
__global__ void pack_kernel(const float* __restrict__ W1,
                            const float* __restrict__ W2,
                            const double* __restrict__ part,
                            unsigned* __restrict__ pk,
                            float* __restrict__ fscales) {
  int idx = blockIdx.x * 1024 + threadIdx.x;  // 0..32767
  const double* q = part;
  double sA = 1.47 * ((((q[0]+q[1])+(q[2]+q[3]))+((q[4]+q[5])+(q[6]+q[7]))) / 131072.0) + 1e-8;
  double sB = 1.47 * ((((q[8]+q[9])+(q[10]+q[11]))+((q[12]+q[13])+(q[14]+q[15]))) / 131072.0) + 1e-8;
  if (idx == 0) { fscales[0] = (float)sA; fscales[1] = (float)sB; }
  bool is2 = idx >= 16384;
  int r = idx & 16383;
  int t = r >> 5;                 // owner thread 0..511
  int w = r & 31;
  int wv = t >> 6, lane = t & 63;
  int l15 = lane & 15, g = (lane >> 4) & 3, wq = wv >> 1;
  unsigned word = 0;
  for (int c = 0; c < 4; ++c) {
    for (int b = 0; b < 4; ++b) {
      int j = 2 * b + (c & 1), kkl = c >> 1;
      int code;
      if (!is2) {
        int mf = w >> 2, kp = w & 3;
        int row = 128 * wq + 16 * mf + l15;
        int k = (2 * kp + kkl) * 32 + 8 * g + j;
        double v = rint((double)W1[row * 256 + k] / sA);
        code = (int)fmin(fmax(v, -2.0), 1.0) & 3;
      } else {
        int mf = w >> 3, kp = w & 7;
        int row = 64 * wq + 16 * mf + l15;
        int k = (2 * kp + kkl) * 32 + 8 * g + j;
        double v = rint((double)W2[row * 512 + k] / sB);
        code = (int)fmin(fmax(v, -2.0), 1.0) & 3;
      }
      word |= (unsigned)code << (8 * b + 2 * c);
    }
  }
  pk[idx] = word;
}

// ---------------- fused MLP kernel ------------------------------------------
// 512 blocks x 512 threads (8 waves), 1 resident block/CU (131KB LDS), 8
// tiles of 64 batch rows. Wave wv (wq=wv>>1, nh=wv&1):
//   L1: hidden rows [128wq,128wq+128) x batch cols [32nh,32nh+32)  (acc1 8x2)
//   L2: out cols   [64wq, 64wq+64)   x batch cols [32nh,32nh+32)  (acc2 4x2)
// Per tile: L1 -> barA -> DMA x(i+1) + epi1 -> barB -> L2 + stores ->
// vmcnt(8) -> barC.  xs holds f32 (DMA, source-swizzled); cvt at frag read.
__launch_bounds__(512, 2)
__global__ void fused_mlp(const float* __restrict__ x,
                          const float* __restrict__ b1,
                          const float* __restrict__ b2,
                          const unsigned* __restrict__ pk,
                          const float* __restrict__ fscales,
                          float* __restrict__ out) {
  __shared__ float xs[BM * D_IN];               // 64 KB f32 (DMA target)
  __shared__ unsigned short hs[BM * D_HID];     // 64 KB bf16
  __shared__ float bs[D_HID + D_OUT];           // 3 KB biases
  const int t = threadIdx.x;
  const int lane = t & 63;
  const int wv = t >> 6;       // 0..7
  const int wq = wv >> 1;      // 0..3
  const int nh = wv & 1;       // batch half
  const int l15 = lane & 15;
  const int g = lane >> 4;     // 0..3
  const long tbase = (long)blockIdx.x * TILES;
  const float s1 = fscales[0], s2 = fscales[1];
  const f32x4 zero4 = {0.f, 0.f, 0.f, 0.f};

  // ---- packed weight codes: 64 u32/lane, resident for the whole kernel
  unsigned w1k[32], w2k[32];
  {
    const uint4* p1 = (const uint4*)pk + t * 8;
    const uint4* p2 = (const uint4*)pk + 4096 + t * 8;
#pragma unroll
    for (int i = 0; i < 8; ++i) {
      uint4 a = p1[i], b = p2[i];
      w1k[4 * i] = a.x; w1k[4 * i + 1] = a.y; w1k[4 * i + 2] = a.z; w1k[4 * i + 3] = a.w;
      w2k[4 * i] = b.x; w2k[4 * i + 1] = b.y; w2k[4 * i + 2] = b.z; w2k[4 * i + 3] = b.w;
    }
  }

  // ---- DMA one x tile (f32) into xs; source swizzled so LDS slot s of row m
  // holds global 16B-chunk s^(m&7). Wave wv stages rows [8wv, 8wv+8).
  auto dma_x = [&](long tile) {
    const float* base = x + tile * (BM * D_IN);
#pragma unroll
    for (int r = 0; r < 8; ++r) {
      int m = wv * 8 + r;                      // m&7 == r
      gload_lds16(base + m * 256 + ((lane ^ r) * 4), &xs[m * 256]);
    }
  };

  // ---- prologue: biases -> LDS, DMA tile 0
  if (t < 192) {
    float4 v = (t < 128) ? ((const float4*)b1)[t] : ((const float4*)b2)[t - 128];
    ((float4*)bs)[t] = v;
  }
  dma_x(tbase);
  asm volatile("s_waitcnt vmcnt(0) lgkmcnt(0)" ::: "memory");
  __builtin_amdgcn_s_barrier();

  f32x4 acc1[8][2];
  f32x4 acc2[4][2];

  for (int i = 0; i < TILES; ++i) {
    // ========== L1: acc1 = W1q * xs^T (K=256, 8 kk) ==========
#pragma unroll
    for (int a = 0; a < 8; ++a) { acc1[a][0] = zero4; acc1[a][1] = zero4; }
#pragma unroll
    for (int kp = 0; kp < 4; ++kp) {
#pragma unroll
      for (int kkl = 0; kkl < 2; ++kkl) {
        int kk = 2 * kp + kkl;
        bf16x8 bx[2];
#pragma unroll
        for (int nf = 0; nf < 2; ++nf) {
          int m = 32 * nh + 16 * nf + l15;
          int c4 = kk * 8 + g * 2;             // 16B chunk (bit0 = 0)
          float4 lo = *(const float4*)&xs[m * 256 + ((c4) ^ (m & 7)) * 4];
          float4 hi = *(const float4*)&xs[m * 256 + ((c4 + 1) ^ (m & 7)) * 4];
          bx[nf] = cvt8(lo, hi);
        }
#pragma unroll
        for (int mf = 0; mf < 8; ++mf) {
          bf16x8 fr = unpack8(w1k[mf * 4 + kp], kkl);
          acc1[mf][0] = __builtin_amdgcn_mfma_f32_16x16x32_bf16(fr, bx[0], acc1[mf][0], 0, 0, 0);
          acc1[mf][1] = __builtin_amdgcn_mfma_f32_16x16x32_bf16(fr, bx[1], acc1[mf][1], 0, 0, 0);
        }
      }
    }
    asm volatile("s_waitcnt lgkmcnt(0)" ::: "memory");
    __builtin_amdgcn_s_barrier();              // A: all waves done reading xs(i)

    if (i + 1 < TILES) dma_x(tbase + i + 1);   // async DMA x(i+1) -> xs

    // ========== epi1: hs = relu(s1*acc1 + b1), swizzled ==========
#pragma unroll
    for (int mf = 0; mf < 8; ++mf) {
      int cb = 128 * wq + 16 * mf + 4 * g;
      float4 bb = *(const float4*)&bs[cb];
      int slot_base = cb >> 3;
      int half = (g & 1) * 4;
#pragma unroll
      for (int nf = 0; nf < 2; ++nf) {
        int m = 32 * nh + 16 * nf + l15;
        f32x4 a = acc1[mf][nf];
        us4 o;
        o.x = f2bf(fmaxf(s1 * a[0] + bb.x, 0.f));
        o.y = f2bf(fmaxf(s1 * a[1] + bb.y, 0.f));
        o.z = f2bf(fmaxf(s1 * a[2] + bb.z, 0.f));
        o.w = f2bf(fmaxf(s1 * a[3] + bb.w, 0.f));
        int slot = slot_base ^ (m & 7);
        *(us4*)&hs[m * 512 + slot * 8 + half] = o;
      }
    }
    asm volatile("s_waitcnt lgkmcnt(0)" ::: "memory");
    __builtin_amdgcn_s_barrier();              // B: hs(i) published

    // ========== L2: acc2 = W2q * hs^T (K=512, 16 kk) ==========
#pragma unroll
    for (int a = 0; a < 4; ++a) { acc2[a][0] = zero4; acc2[a][1] = zero4; }
#pragma unroll
    for (int kp = 0; kp < 8; ++kp) {
#pragma unroll
      for (int kkl = 0; kkl < 2; ++kkl) {
        int kk = 2 * kp + kkl;
        bf16x8 bh[2];
#pragma unroll
        for (int nf = 0; nf < 2; ++nf) {
          int m = 32 * nh + 16 * nf + l15;
          int slot = (kk * 4 + g) ^ (m & 7);
          bh[nf] = *(const bf16x8*)&hs[m * 512 + slot * 8];
        }
#pragma unroll
        for (int mf = 0; mf < 4; ++mf) {
          bf16x8 fr = unpack8(w2k[mf * 8 + kp], kkl);
          acc2[mf][0] = __builtin_amdgcn_mfma_f32_16x16x32_bf16(fr, bh[0], acc2[mf][0], 0, 0, 0);
          acc2[mf][1] = __builtin_amdgcn_mfma_f32_16x16x32_bf16(fr, bh[1], acc2[mf][1], 0, 0, 0);
        }
      }
    }
    // ========== epi2: out stores (fire and forget) ==========
    {
      const long row0 = (tbase + i) * BM;
#pragma unroll
      for (int mf = 0; mf < 4; ++mf) {
        int n4 = 64 * wq + 16 * mf + 4 * g;
        float4 bb = *(const float4*)&bs[512 + n4];
#pragma unroll
        for (int nf = 0; nf < 2; ++nf) {
          int m = 32 * nh + 16 * nf + l15;
          f32x4 a = acc2[mf][nf];
          float4 o;
          o.x = s2 * a[0] + bb.x;
          o.y = s2 * a[1] + bb.y;
          o.z = s2 * a[2] + bb.z;
          o.w = s2 * a[3] + bb.w;
          *(float4*)&out[(row0 + m) * D_OUT + n4] = o;
        }
      }
    }
    // DMA (8, issued before the 8 stores) must be done; stores may fly.
    asm volatile("s_waitcnt vmcnt(8)" ::: "memory");
    __builtin_amdgcn_s_barrier();              // C: xs(i+1) ready for all
  }
}

extern "C" void kernel_launch(void* const* d_in, const int* in_sizes, int n_in,
                              void* d_out, int out_size, void* d_ws, size_t ws_size,
                              hipStream_t stream) {
  const float* x  = (const float*)d_in[0];
  const float* W1 = (const float*)d_in[1];
  const float* b1 = (const float*)d_in[2];
  const float* W2 = (const float*)d_in[3];
  const float* b2 = (const float*)d_in[4];
  float* out = (float*)d_out;

  // ws layout: [0,128) f64 partials, [128,136) f32 scales, pk at 1024 (128 KB)
  double* part = (double*)d_ws;
  float* fsc = (float*)((char*)d_ws + 128);
  unsigned* pk = (unsigned*)((char*)d_ws + 1024);

  int Brows = in_sizes[0] / D_IN;     // 262144
  int nblk = Brows / (BM * TILES);    // 512

  partial_abs_kernel<<<dim3(16), dim3(1024), 0, stream>>>(W1, W2, part);
  pack_kernel<<<dim3(32), dim3(1024), 0, stream>>>(W1, W2, part, pk, fsc);
  fused_mlp<<<dim3(nblk), dim3(512), 0, stream>>>(x, b1, b2, pk, fsc, out);
}

// Round 9
// 610.258 us; speedup vs baseline: 1.6715x; 1.6715x over previous
//
#include <hip/hip_runtime.h>
#include <hip/hip_bf16.h>

// Problem: out = lecac_linear(relu(lecac_linear(x, W1, b1)), W2, b2)
//   x: [262144, 256] f32, W1: [512,256], b1: [512], W2: [256,512], b2: [256]
// R9: UNFUSED two-pass streaming GEMMs. R4-R8's fused designs all either
// spilled (compiler allocates ~128 VGPR regardless of launch_bounds; resident
// weights/prefetch pushed past it -> scratch traffic 3-7x ideal) or phase-
// serialized at 1 block/CU. Now: K1 x->h, K2 h->out, h bounced through d_out
// (268MB bf16 == d_out's 268MB f32 byte size). No LDS, no lockstep barriers,
// ~80 live regs/wave, 8192 independent blocks per kernel -> latency hidden by
// TLP. K2 is in-place per 32-row stripe (vmcnt(0)+s_barrier between the
// block's last h-read and first out-store; blocks own disjoint rows).
// Weights stay packed 2-bit codes (16 u32/lane), unpacked via v_perm LUT
// (numerics verified R7/R8: absmax 0.03125).

typedef __attribute__((ext_vector_type(8))) short bf16x8;
typedef __attribute__((ext_vector_type(4))) float f32x4;
typedef __attribute__((ext_vector_type(4))) unsigned short us4;

#define D_IN 256
#define D_HID 512
#define D_OUT 256
#define BM 32

__device__ __forceinline__ unsigned short f2bf(float f) {
  union { __hip_bfloat16 h; unsigned short u; } c;
  c.h = __float2bfloat16(f);
  return c.u;
}

__device__ __forceinline__ bf16x8 cvt8(float4 lo, float4 hi) {
  bf16x8 v;
  v[0] = (short)f2bf(lo.x); v[1] = (short)f2bf(lo.y);
  v[2] = (short)f2bf(lo.z); v[3] = (short)f2bf(lo.w);
  v[4] = (short)f2bf(hi.x); v[5] = (short)f2bf(hi.y);
  v[6] = (short)f2bf(hi.z); v[7] = (short)f2bf(hi.w);
  return v;
}

// Unpack 8 codes (half of a 16-code u32, selected by kkl) -> bf16x8.
// Code c (2 bits): 0->0.0, 1->1.0, 2->-2.0, 3->-1.0. (verified R7/R8)
__device__ __forceinline__ bf16x8 unpack8(unsigned w, int kkl) {
  unsigned te = (w >> (4 * kkl)) & 0x03030303u;        // els j = 0,2,4,6
  unsigned to = (w >> (4 * kkl + 2)) & 0x03030303u;    // els j = 1,3,5,7
  int4 o;
  unsigned s;
  s = __builtin_amdgcn_perm(to, te, 0x04040000u) + 0x00040004u;
  o.x = (int)__builtin_amdgcn_perm(0x80008000u, 0xBFC03F00u, s);
  s = __builtin_amdgcn_perm(to, te, 0x05050101u) + 0x00040004u;
  o.y = (int)__builtin_amdgcn_perm(0x80008000u, 0xBFC03F00u, s);
  s = __builtin_amdgcn_perm(to, te, 0x06060202u) + 0x00040004u;
  o.z = (int)__builtin_amdgcn_perm(0x80008000u, 0xBFC03F00u, s);
  s = __builtin_amdgcn_perm(to, te, 0x07070303u) + 0x00040004u;
  o.w = (int)__builtin_amdgcn_perm(0x80008000u, 0xBFC03F00u, s);
  return *(bf16x8*)&o;
}

// ---- prep 1: deterministic f64 partial abs-sums (8 chunks per tensor) ------
__global__ void partial_abs_kernel(const float* __restrict__ W1,
                                   const float* __restrict__ W2,
                                   double* __restrict__ part) {
  const int b = blockIdx.x;                 // 0..15
  const float* W = (b < 8) ? W1 : W2;
  const float* p = W + (b & 7) * 16384;     // 131072 / 8
  double s = 0.0;
  for (int i = threadIdx.x; i < 16384; i += 1024) s += (double)fabsf(p[i]);
  __shared__ double red[1024];
  red[threadIdx.x] = s;
  __syncthreads();
  for (int st = 512; st > 0; st >>= 1) {
    if (threadIdx.x < st) red[threadIdx.x] += red[threadIdx.x + st];
    __syncthreads();
  }
  if (threadIdx.x == 0) part[b] = red[0];
}

// ---- prep 2: pack 2-bit codes in the per-lane fragment order ---------------
// Region 1 (W1, words 0..8191):  word = tt*16 + mf*4 + kp  (mf<4, kp<4)
//   frag row = 64*wv + 16*mf + l15,  k = (2*kp+kkl)*32 + 8*g + j
// Region 2 (W2, words 8192..16383): word = 8192 + tt*16 + mf*8 + kp (mf<2,kp<8)
//   frag row = 32*wv + 16*mf + l15,  k = (2*kp+kkl)*32 + 8*g + j
// Crumb (byte b, crumb c): j = 2b + (c&1), kkl = c>>1.
__global__ void pack_kernel(const float* __restrict__ W1,
                            const float* __restrict__ W2,
                            const double* __restrict__ part,
                            unsigned* __restrict__ pk,
                            float* __restrict__ fscales) {
  int idx = blockIdx.x * 1024 + threadIdx.x;  // 0..16383
  const double* q = part;
  double sA = 1.47 * ((((q[0]+q[1])+(q[2]+q[3]))+((q[4]+q[5])+(q[6]+q[7]))) / 131072.0) + 1e-8;
  double sB = 1.47 * ((((q[8]+q[9])+(q[10]+q[11]))+((q[12]+q[13])+(q[14]+q[15]))) / 131072.0) + 1e-8;
  if (idx == 0) { fscales[0] = (float)sA; fscales[1] = (float)sB; }
  bool is2 = idx >= 8192;
  int r = idx & 8191;
  int tt = r >> 4;                // owner thread 0..511
  int w = r & 15;
  int wv = tt >> 6, lane = tt & 63;
  int l15 = lane & 15, g = (lane >> 4) & 3;
  unsigned word = 0;
  for (int c = 0; c < 4; ++c) {
    for (int b = 0; b < 4; ++b) {
      int j = 2 * b + (c & 1), kkl = c >> 1;
      int code;
      if (!is2) {
        int mf = w >> 2, kp = w & 3;
        int row = 64 * wv + 16 * mf + l15;
        int k = (2 * kp + kkl) * 32 + 8 * g + j;
        double v = rint((double)W1[row * 256 + k] / sA);
        code = (int)fmin(fmax(v, -2.0), 1.0) & 3;
      } else {
        int mf = w >> 3, kp = w & 7;
        int row = 32 * wv + 16 * mf + l15;
        int k = (2 * kp + kkl) * 32 + 8 * g + j;
        double v = rint((double)W2[row * 512 + k] / sB);
        code = (int)fmin(fmax(v, -2.0), 1.0) & 3;
      }
      word |= (unsigned)code << (8 * b + 2 * c);
    }
  }
  pk[idx] = word;
}

// ---------------- K1: h = relu(s1 * (W1q @ x^T) + b1), h bf16 ---------------
// 8192 blocks x 512 threads. Block = 32 batch rows. Wave wv owns hidden rows
// [64wv, 64wv+64). x B-frags read directly from global f32 (L1/L2-served
// redundancy), cvt to bf16 at use. No LDS, no barriers.
__launch_bounds__(512, 4)
__global__ void k1_gemm(const float* __restrict__ x,
                        const float* __restrict__ b1,
                        const unsigned* __restrict__ pk,
                        const float* __restrict__ fscales,
                        unsigned short* __restrict__ h) {
  const int t = threadIdx.x;
  const int lane = t & 63;
  const int wv = t >> 6;
  const int l15 = lane & 15;
  const int g = lane >> 4;
  const long row0 = (long)blockIdx.x * BM;
  const float s1 = fscales[0];
  const f32x4 zero4 = {0.f, 0.f, 0.f, 0.f};

  unsigned w1k[16];
  {
    const uint4* p = (const uint4*)pk + t * 4;
#pragma unroll
    for (int i = 0; i < 4; ++i) {
      uint4 a = p[i];
      w1k[4*i] = a.x; w1k[4*i+1] = a.y; w1k[4*i+2] = a.z; w1k[4*i+3] = a.w;
    }
  }

  f32x4 acc[4][2];
#pragma unroll
  for (int a = 0; a < 4; ++a) { acc[a][0] = zero4; acc[a][1] = zero4; }

#pragma unroll
  for (int kp = 0; kp < 4; ++kp) {
#pragma unroll
    for (int kkl = 0; kkl < 2; ++kkl) {
      int kk = 2 * kp + kkl;
      bf16x8 bx[2];
#pragma unroll
      for (int nf = 0; nf < 2; ++nf) {
        int m = 16 * nf + l15;
        const float4* p = (const float4*)&x[(row0 + m) * D_IN + kk * 32 + g * 8];
        bx[nf] = cvt8(p[0], p[1]);
      }
#pragma unroll
      for (int mf = 0; mf < 4; ++mf) {
        bf16x8 fr = unpack8(w1k[mf * 4 + kp], kkl);
        acc[mf][0] = __builtin_amdgcn_mfma_f32_16x16x32_bf16(fr, bx[0], acc[mf][0], 0, 0, 0);
        acc[mf][1] = __builtin_amdgcn_mfma_f32_16x16x32_bf16(fr, bx[1], acc[mf][1], 0, 0, 0);
      }
    }
  }

  // epilogue: h[m][c] = relu(s1*acc + b1[c]), 8B stores (4 consecutive hidden)
#pragma unroll
  for (int mf = 0; mf < 4; ++mf) {
    int cb = 64 * wv + 16 * mf + 4 * g;
    float4 bb = *(const float4*)&b1[cb];
#pragma unroll
    for (int nf = 0; nf < 2; ++nf) {
      int m = 16 * nf + l15;
      f32x4 a = acc[mf][nf];
      us4 o;
      o.x = f2bf(fmaxf(s1 * a[0] + bb.x, 0.f));
      o.y = f2bf(fmaxf(s1 * a[1] + bb.y, 0.f));
      o.z = f2bf(fmaxf(s1 * a[2] + bb.z, 0.f));
      o.w = f2bf(fmaxf(s1 * a[3] + bb.w, 0.f));
      *(us4*)&h[(row0 + m) * D_HID + cb] = o;
    }
  }
}

// ---------------- K2: out = s2 * (W2q @ h^T) + b2, f32, IN-PLACE over h -----
// 8192 blocks x 512 threads. Block = 32 batch rows. Wave wv owns out cols
// [32wv, 32wv+32). h B-frags read directly from global bf16. In-place: all
// h-reads of the block complete (vmcnt(0) + s_barrier) before any out-store.
__launch_bounds__(512, 4)
__global__ void k2_gemm(const unsigned short* __restrict__ h,
                        const float* __restrict__ b2,
                        const unsigned* __restrict__ pk2,
                        const float* __restrict__ fscales,
                        float* __restrict__ out) {
  const int t = threadIdx.x;
  const int lane = t & 63;
  const int wv = t >> 6;
  const int l15 = lane & 15;
  const int g = lane >> 4;
  const long row0 = (long)blockIdx.x * BM;
  const float s2 = fscales[1];
  const f32x4 zero4 = {0.f, 0.f, 0.f, 0.f};

  unsigned w2k[16];
  {
    const uint4* p = (const uint4*)pk2 + t * 4;
#pragma unroll
    for (int i = 0; i < 4; ++i) {
      uint4 a = p[i];
      w2k[4*i] = a.x; w2k[4*i+1] = a.y; w2k[4*i+2] = a.z; w2k[4*i+3] = a.w;
    }
  }

  f32x4 acc[2][2];
#pragma unroll
  for (int a = 0; a < 2; ++a) { acc[a][0] = zero4; acc[a][1] = zero4; }

#pragma unroll
  for (int kp = 0; kp < 8; ++kp) {
#pragma unroll
    for (int kkl = 0; kkl < 2; ++kkl) {
      int kk = 2 * kp + kkl;
      bf16x8 bh[2];
#pragma unroll
      for (int nf = 0; nf < 2; ++nf) {
        int m = 16 * nf + l15;
        bh[nf] = *(const bf16x8*)&h[(row0 + m) * D_HID + kk * 32 + g * 8];
      }
#pragma unroll
      for (int mf = 0; mf < 2; ++mf) {
        bf16x8 fr = unpack8(w2k[mf * 8 + kp], kkl);
        acc[mf][0] = __builtin_amdgcn_mfma_f32_16x16x32_bf16(fr, bh[0], acc[mf][0], 0, 0, 0);
        acc[mf][1] = __builtin_amdgcn_mfma_f32_16x16x32_bf16(fr, bh[1], acc[mf][1], 0, 0, 0);
      }
    }
  }

  // all h-reads of this block's rows are done before any lane overwrites them
  asm volatile("s_waitcnt vmcnt(0)" ::: "memory");
  __builtin_amdgcn_s_barrier();

#pragma unroll
  for (int mf = 0; mf < 2; ++mf) {
    int n4 = 32 * wv + 16 * mf + 4 * g;
    float4 bb = *(const float4*)&b2[n4];
#pragma unroll
    for (int nf = 0; nf < 2; ++nf) {
      int m = 16 * nf + l15;
      f32x4 a = acc[mf][nf];
      float4 o;
      o.x = s2 * a[0] + bb.x;
      o.y = s2 * a[1] + bb.y;
      o.z = s2 * a[2] + bb.z;
      o.w = s2 * a[3] + bb.w;
      *(float4*)&out[(row0 + m) * D_OUT + n4] = o;
    }
  }
}

extern "C" void kernel_launch(void* const* d_in, const int* in_sizes, int n_in,
                              void* d_out, int out_size, void* d_ws, size_t ws_size,
                              hipStream_t stream) {
  const float* x  = (const float*)d_in[0];
  const float* W1 = (const float*)d_in[1];
  const float* b1 = (const float*)d_in[2];
  const float* W2 = (const float*)d_in[3];
  const float* b2 = (const float*)d_in[4];
  float* out = (float*)d_out;

  // ws layout: [0,128) f64 partials, [128,136) f32 scales, pk at 1024 (64 KB)
  double* part = (double*)d_ws;
  float* fsc = (float*)((char*)d_ws + 128);
  unsigned* pk = (unsigned*)((char*)d_ws + 1024);

  // h (262144 x 512 bf16 = 268 MB) lives in d_out (262144 x 256 f32 = 268 MB)
  unsigned short* hbuf = (unsigned short*)d_out;

  int Brows = in_sizes[0] / D_IN;     // 262144
  int nblk = Brows / BM;              // 8192

  partial_abs_kernel<<<dim3(16), dim3(1024), 0, stream>>>(W1, W2, part);
  pack_kernel<<<dim3(16), dim3(1024), 0, stream>>>(W1, W2, part, pk, fsc);
  k1_gemm<<<dim3(nblk), dim3(512), 0, stream>>>(x, b1, pk, fsc, hbuf);
  k2_gemm<<<dim3(nblk), dim3(512), 0, stream>>>(hbuf, b2, pk + 8192, fsc, out);
}

// Round 10
// 289.713 us; speedup vs baseline: 3.5209x; 2.1064x over previous
//
#include <hip/hip_runtime.h>
#include <hip/hip_bf16.h>

// Problem: out = lecac_linear(relu(lecac_linear(x, W1, b1)), W2, b2)
//   x: [262144, 256] f32, W1: [512,256], b1: [512], W2: [256,512], b2: [256]
// R10: unfused two-pass (R9 skeleton: no spills, no phase-lock) + LDS staging.
// R9's k1 was latency-bound (all pipes <25%): per-kk global x-frag loads
// (L2/L3 ~200-600cyc) serialized against MFMA with only ~5 waves/SIMD.
// Now each block stages its activation tile into LDS once (k1: reg-staged
// f32->bf16 16KB; k2: global_load_lds DMA of bf16 h, 32KB), B-frags read from
// LDS. XOR swizzle slot^((row&7)<<2) on both write and read sides (<=4-way
// residual, ~free). k2 in-place safety: h-reads all happen in the DMA stage,
// ordered before stores by the post-stage barrier; blocks own disjoint rows.
// Weights stay packed 2-bit codes (16 u32/lane), v_perm LUT unpack (verified
// R7-R9, absmax 0.03125). h bounced through d_out (268MB bf16 == d_out size).

typedef __attribute__((ext_vector_type(8))) short bf16x8;
typedef __attribute__((ext_vector_type(4))) float f32x4;
typedef __attribute__((ext_vector_type(4))) unsigned short us4;

#define D_IN 256
#define D_HID 512
#define D_OUT 256
#define BM 32

__device__ __forceinline__ unsigned short f2bf(float f) {
  union { __hip_bfloat16 h; unsigned short u; } c;
  c.h = __float2bfloat16(f);
  return c.u;
}

__device__ __forceinline__ bf16x8 cvt8(float4 lo, float4 hi) {
  bf16x8 v;
  v[0] = (short)f2bf(lo.x); v[1] = (short)f2bf(lo.y);
  v[2] = (short)f2bf(lo.z); v[3] = (short)f2bf(lo.w);
  v[4] = (short)f2bf(hi.x); v[5] = (short)f2bf(hi.y);
  v[6] = (short)f2bf(hi.z); v[7] = (short)f2bf(hi.w);
  return v;
}

// DMA 16B per lane: global (per-lane addr) -> LDS (wave-uniform base + lane*16)
__device__ __forceinline__ void gload_lds16(const unsigned short* g, unsigned short* l) {
  __builtin_amdgcn_global_load_lds(
      (const __attribute__((address_space(1))) void*)(const void*)g,
      (__attribute__((address_space(3))) void*)(void*)l, 16, 0, 0);
}

// Unpack 8 codes (half of a 16-code u32, selected by kkl) -> bf16x8.
// Code c (2 bits): 0->0.0, 1->1.0, 2->-2.0, 3->-1.0. (verified R7-R9)
__device__ __forceinline__ bf16x8 unpack8(unsigned w, int kkl) {
  unsigned te = (w >> (4 * kkl)) & 0x03030303u;        // els j = 0,2,4,6
  unsigned to = (w >> (4 * kkl + 2)) & 0x03030303u;    // els j = 1,3,5,7
  int4 o;
  unsigned s;
  s = __builtin_amdgcn_perm(to, te, 0x04040000u) + 0x00040004u;
  o.x = (int)__builtin_amdgcn_perm(0x80008000u, 0xBFC03F00u, s);
  s = __builtin_amdgcn_perm(to, te, 0x05050101u) + 0x00040004u;
  o.y = (int)__builtin_amdgcn_perm(0x80008000u, 0xBFC03F00u, s);
  s = __builtin_amdgcn_perm(to, te, 0x06060202u) + 0x00040004u;
  o.z = (int)__builtin_amdgcn_perm(0x80008000u, 0xBFC03F00u, s);
  s = __builtin_amdgcn_perm(to, te, 0x07070303u) + 0x00040004u;
  o.w = (int)__builtin_amdgcn_perm(0x80008000u, 0xBFC03F00u, s);
  return *(bf16x8*)&o;
}

// ---- prep 1: deterministic f64 partial abs-sums (8 chunks per tensor) ------
__global__ void partial_abs_kernel(const float* __restrict__ W1,
                                   const float* __restrict__ W2,
                                   double* __restrict__ part) {
  const int b = blockIdx.x;                 // 0..15
  const float* W = (b < 8) ? W1 : W2;
  const float* p = W + (b & 7) * 16384;     // 131072 / 8
  double s = 0.0;
  for (int i = threadIdx.x; i < 16384; i += 1024) s += (double)fabsf(p[i]);
  __shared__ double red[1024];
  red[threadIdx.x] = s;
  __syncthreads();
  for (int st = 512; st > 0; st >>= 1) {
    if (threadIdx.x < st) red[threadIdx.x] += red[threadIdx.x + st];
    __syncthreads();
  }
  if (threadIdx.x == 0) part[b] = red[0];
}

// ---- prep 2: pack 2-bit codes in the per-lane fragment order ---------------
// Region 1 (W1, words 0..8191):  word = tt*16 + mf*4 + kp  (mf<4, kp<4)
//   frag row = 64*wv + 16*mf + l15,  k = (2*kp+kkl)*32 + 8*g + j
// Region 2 (W2, words 8192..16383): word = 8192 + tt*16 + mf*8 + kp (mf<2,kp<8)
//   frag row = 32*wv + 16*mf + l15,  k = (2*kp+kkl)*32 + 8*g + j
// Crumb (byte b, crumb c): j = 2b + (c&1), kkl = c>>1.
__global__ void pack_kernel(const float* __restrict__ W1,
                            const float* __restrict__ W2,
                            const double* __restrict__ part,
                            unsigned* __restrict__ pk,
                            float* __restrict__ fscales) {
  int idx = blockIdx.x * 1024 + threadIdx.x;  // 0..16383
  const double* q = part;
  double sA = 1.47 * ((((q[0]+q[1])+(q[2]+q[3]))+((q[4]+q[5])+(q[6]+q[7]))) / 131072.0) + 1e-8;
  double sB = 1.47 * ((((q[8]+q[9])+(q[10]+q[11]))+((q[12]+q[13])+(q[14]+q[15]))) / 131072.0) + 1e-8;
  if (idx == 0) { fscales[0] = (float)sA; fscales[1] = (float)sB; }
  bool is2 = idx >= 8192;
  int r = idx & 8191;
  int tt = r >> 4;                // owner thread 0..511
  int w = r & 15;
  int wv = tt >> 6, lane = tt & 63;
  int l15 = lane & 15, g = (lane >> 4) & 3;
  unsigned word = 0;
  for (int c = 0; c < 4; ++c) {
    for (int b = 0; b < 4; ++b) {
      int j = 2 * b + (c & 1), kkl = c >> 1;
      int code;
      if (!is2) {
        int mf = w >> 2, kp = w & 3;
        int row = 64 * wv + 16 * mf + l15;
        int k = (2 * kp + kkl) * 32 + 8 * g + j;
        double v = rint((double)W1[row * 256 + k] / sA);
        code = (int)fmin(fmax(v, -2.0), 1.0) & 3;
      } else {
        int mf = w >> 3, kp = w & 7;
        int row = 32 * wv + 16 * mf + l15;
        int k = (2 * kp + kkl) * 32 + 8 * g + j;
        double v = rint((double)W2[row * 512 + k] / sB);
        code = (int)fmin(fmax(v, -2.0), 1.0) & 3;
      }
      word |= (unsigned)code << (8 * b + 2 * c);
    }
  }
  pk[idx] = word;
}

// ---------------- K1: h = relu(s1 * (W1q @ x^T) + b1), h bf16 ---------------
// 8192 blocks x 512 threads (8 waves). Block = 32 batch rows. Wave wv owns
// hidden rows [64wv, 64wv+64). x tile reg-staged to LDS as bf16 (16 KB),
// swizzled slot^((row&7)<<2); B-frags = single ds_read_b128 each.
__launch_bounds__(512)
__global__ void k1_gemm(const float* __restrict__ x,
                        const float* __restrict__ b1,
                        const unsigned* __restrict__ pk,
                        const float* __restrict__ fscales,
                        unsigned short* __restrict__ h) {
  __shared__ unsigned short xs[BM * D_IN];   // 32 rows x 256 bf16 = 16 KB
  const int t = threadIdx.x;
  const int lane = t & 63;
  const int wv = t >> 6;
  const int l15 = lane & 15;
  const int g = lane >> 4;
  const long row0 = (long)blockIdx.x * BM;
  const float s1 = fscales[0];
  const f32x4 zero4 = {0.f, 0.f, 0.f, 0.f};

  unsigned w1k[16];
  {
    const uint4* p = (const uint4*)pk + t * 4;
#pragma unroll
    for (int i = 0; i < 4; ++i) {
      uint4 a = p[i];
      w1k[4*i] = a.x; w1k[4*i+1] = a.y; w1k[4*i+2] = a.z; w1k[4*i+3] = a.w;
    }
  }

  // ---- stage x tile: thread t covers row r = t>>4, f32 cols (t&15)*16..+16
  {
    const float4* p = (const float4*)x + (long)blockIdx.x * 2048 + (t >> 4) * 64 + (t & 15) * 4;
    float4 v0 = p[0], v1 = p[1], v2 = p[2], v3 = p[3];
    int r = t >> 4, cq = t & 15;
    bf16x8 e0 = cvt8(v0, v1);
    bf16x8 e1 = cvt8(v2, v3);
    int sw = (r & 7) << 2;
    *(bf16x8*)&xs[r * 256 + ((cq * 2) ^ sw) * 8] = e0;
    *(bf16x8*)&xs[r * 256 + ((cq * 2 + 1) ^ sw) * 8] = e1;
  }
  __syncthreads();

  f32x4 acc[4][2];
#pragma unroll
  for (int a = 0; a < 4; ++a) { acc[a][0] = zero4; acc[a][1] = zero4; }

#pragma unroll
  for (int kp = 0; kp < 4; ++kp) {
#pragma unroll
    for (int kkl = 0; kkl < 2; ++kkl) {
      int kk = 2 * kp + kkl;
      bf16x8 bx[2];
#pragma unroll
      for (int nf = 0; nf < 2; ++nf) {
        int m = 16 * nf + l15;
        int s = (kk * 4 + g) ^ ((m & 7) << 2);
        bx[nf] = *(const bf16x8*)&xs[m * 256 + s * 8];
      }
#pragma unroll
      for (int mf = 0; mf < 4; ++mf) {
        bf16x8 fr = unpack8(w1k[mf * 4 + kp], kkl);
        acc[mf][0] = __builtin_amdgcn_mfma_f32_16x16x32_bf16(fr, bx[0], acc[mf][0], 0, 0, 0);
        acc[mf][1] = __builtin_amdgcn_mfma_f32_16x16x32_bf16(fr, bx[1], acc[mf][1], 0, 0, 0);
      }
    }
  }

  // epilogue: h[m][c] = relu(s1*acc + b1[c]), 8B stores (4 consecutive hidden)
#pragma unroll
  for (int mf = 0; mf < 4; ++mf) {
    int cb = 64 * wv + 16 * mf + 4 * g;
    float4 bb = *(const float4*)&b1[cb];
#pragma unroll
    for (int nf = 0; nf < 2; ++nf) {
      int m = 16 * nf + l15;
      f32x4 a = acc[mf][nf];
      us4 o;
      o.x = f2bf(fmaxf(s1 * a[0] + bb.x, 0.f));
      o.y = f2bf(fmaxf(s1 * a[1] + bb.y, 0.f));
      o.z = f2bf(fmaxf(s1 * a[2] + bb.z, 0.f));
      o.w = f2bf(fmaxf(s1 * a[3] + bb.w, 0.f));
      *(us4*)&h[(row0 + m) * D_HID + cb] = o;
    }
  }
}

// ---------------- K2: out = s2 * (W2q @ h^T) + b2, f32, IN-PLACE over h -----
// 8192 blocks x 512 threads. Block = 32 batch rows. Wave wv owns out cols
// [32wv, 32wv+32). h tile DMA-staged to LDS (32 KB) with source-side swizzle;
// all h-reads happen in the stage, so the post-stage barrier orders them
// before any out store (in-place safe; blocks own disjoint rows).
__launch_bounds__(512)
__global__ void k2_gemm(const unsigned short* __restrict__ h,
                        const float* __restrict__ b2,
                        const unsigned* __restrict__ pk2,
                        const float* __restrict__ fscales,
                        float* __restrict__ out) {
  __shared__ unsigned short hs[BM * D_HID];  // 32 rows x 512 bf16 = 32 KB
  const int t = threadIdx.x;
  const int lane = t & 63;
  const int wv = t >> 6;
  const int l15 = lane & 15;
  const int g = lane >> 4;
  const long row0 = (long)blockIdx.x * BM;
  const float s2 = fscales[1];
  const f32x4 zero4 = {0.f, 0.f, 0.f, 0.f};

  unsigned w2k[16];
  {
    const uint4* p = (const uint4*)pk2 + t * 4;
#pragma unroll
    for (int i = 0; i < 4; ++i) {
      uint4 a = p[i];
      w2k[4*i] = a.x; w2k[4*i+1] = a.y; w2k[4*i+2] = a.z; w2k[4*i+3] = a.w;
    }
  }

  // ---- DMA stage h tile: wave wv stages rows 4wv..4wv+3; LDS slot l holds
  // global chunk l ^ ((m&7)<<2)  (so swizzled read finds linear chunk)
#pragma unroll
  for (int j = 0; j < 4; ++j) {
    int m = wv * 4 + j;
    gload_lds16(&h[(row0 + m) * D_HID + ((lane ^ ((m & 7) << 2)) & 63) * 8],
                &hs[m * D_HID]);
  }
  asm volatile("s_waitcnt vmcnt(0)" ::: "memory");
  __syncthreads();

  f32x4 acc[2][2];
#pragma unroll
  for (int a = 0; a < 2; ++a) { acc[a][0] = zero4; acc[a][1] = zero4; }

#pragma unroll
  for (int kp = 0; kp < 8; ++kp) {
#pragma unroll
    for (int kkl = 0; kkl < 2; ++kkl) {
      int kk = 2 * kp + kkl;
      bf16x8 bh[2];
#pragma unroll
      for (int nf = 0; nf < 2; ++nf) {
        int m = 16 * nf + l15;
        int s = (kk * 4 + g) ^ ((m & 7) << 2);
        bh[nf] = *(const bf16x8*)&hs[m * D_HID + s * 8];
      }
#pragma unroll
      for (int mf = 0; mf < 2; ++mf) {
        bf16x8 fr = unpack8(w2k[mf * 8 + kp], kkl);
        acc[mf][0] = __builtin_amdgcn_mfma_f32_16x16x32_bf16(fr, bh[0], acc[mf][0], 0, 0, 0);
        acc[mf][1] = __builtin_amdgcn_mfma_f32_16x16x32_bf16(fr, bh[1], acc[mf][1], 0, 0, 0);
      }
    }
  }

#pragma unroll
  for (int mf = 0; mf < 2; ++mf) {
    int n4 = 32 * wv + 16 * mf + 4 * g;
    float4 bb = *(const float4*)&b2[n4];
#pragma unroll
    for (int nf = 0; nf < 2; ++nf) {
      int m = 16 * nf + l15;
      f32x4 a = acc[mf][nf];
      float4 o;
      o.x = s2 * a[0] + bb.x;
      o.y = s2 * a[1] + bb.y;
      o.z = s2 * a[2] + bb.z;
      o.w = s2 * a[3] + bb.w;
      *(float4*)&out[(row0 + m) * D_OUT + n4] = o;
    }
  }
}

extern "C" void kernel_launch(void* const* d_in, const int* in_sizes, int n_in,
                              void* d_out, int out_size, void* d_ws, size_t ws_size,
                              hipStream_t stream) {
  const float* x  = (const float*)d_in[0];
  const float* W1 = (const float*)d_in[1];
  const float* b1 = (const float*)d_in[2];
  const float* W2 = (const float*)d_in[3];
  const float* b2 = (const float*)d_in[4];
  float* out = (float*)d_out;

  // ws layout: [0,128) f64 partials, [128,136) f32 scales, pk at 1024 (64 KB)
  double* part = (double*)d_ws;
  float* fsc = (float*)((char*)d_ws + 128);
  unsigned* pk = (unsigned*)((char*)d_ws + 1024);

  // h (262144 x 512 bf16 = 268 MB) lives in d_out (262144 x 256 f32 = 268 MB)
  unsigned short* hbuf = (unsigned short*)d_out;

  int Brows = in_sizes[0] / D_IN;     // 262144
  int nblk = Brows / BM;              // 8192

  partial_abs_kernel<<<dim3(16), dim3(1024), 0, stream>>>(W1, W2, part);
  pack_kernel<<<dim3(16), dim3(1024), 0, stream>>>(W1, W2, part, pk, fsc);
  k1_gemm<<<dim3(nblk), dim3(512), 0, stream>>>(x, b1, pk, fsc, hbuf);
  k2_gemm<<<dim3(nblk), dim3(512), 0, stream>>>(hbuf, b2, pk + 8192, fsc, out);
}